// Round 1
// baseline (1320.632 us; speedup 1.0000x reference)
//
#include <hip/hip_runtime.h>

#define N_NODES 100000
#define N_EDGES 3200000
#define IN_DIM 500
#define HID 16
#define OUT_DIM 500

// ---------- degree / norm ----------
__global__ void k_set1(float* __restrict__ d, int n) {
    int i = blockIdx.x * blockDim.x + threadIdx.x;
    if (i < n) d[i] = 1.0f;  // self-loop contributes 1 to every node's degree
}

__global__ void k_deg(const int* __restrict__ dst, float* __restrict__ deg, int E) {
    int e = blockIdx.x * blockDim.x + threadIdx.x;
    if (e < E) atomicAdd(&deg[dst[e]], 1.0f);
}

__global__ void k_rsqrt(float* __restrict__ d, int n) {
    int i = blockIdx.x * blockDim.x + threadIdx.x;
    if (i < n) d[i] = rsqrtf(d[i]);  // deg >= 1 always (self-loops), no zero check needed
}

// ---------- h[N,16] = x[N,500] @ W[500,16] ----------
__global__ __launch_bounds__(256) void k_mm1(const float* __restrict__ x,
                                             const float* __restrict__ W,
                                             float* __restrict__ h) {
    __shared__ float Ws[IN_DIM * HID];  // 32000 B
    for (int t = threadIdx.x; t < IN_DIM * HID; t += 256) Ws[t] = W[t];
    __syncthreads();
    int i = blockIdx.x * 16 + (threadIdx.x >> 4);
    int j = threadIdx.x & 15;
    if (i >= N_NODES) return;
    // row byte offset = i*2000, 2000 % 16 == 0 -> float4 aligned
    const float4* xr = (const float4*)(x + (size_t)i * IN_DIM);
    float acc = 0.0f;
#pragma unroll 5
    for (int k4 = 0; k4 < IN_DIM / 4; ++k4) {
        float4 v = xr[k4];
        acc += v.x * Ws[(4 * k4 + 0) * HID + j];
        acc += v.y * Ws[(4 * k4 + 1) * HID + j];
        acc += v.z * Ws[(4 * k4 + 2) * HID + j];
        acc += v.w * Ws[(4 * k4 + 3) * HID + j];
    }
    h[(size_t)i * HID + j] = acc;
}

// ---------- scatter: agg[dst] += dis[src]*dis[dst] * h[src]  (16 threads per edge) ----------
__global__ __launch_bounds__(256) void k_agg(const int* __restrict__ src,
                                             const int* __restrict__ dst,
                                             const float* __restrict__ dis,
                                             const float* __restrict__ h,
                                             float* __restrict__ agg, int E) {
    int t = blockIdx.x * 256 + threadIdx.x;
    int e = t >> 4;
    if (e >= E) return;
    int f = t & 15;
    int s = src[e];
    int d = dst[e];
    float nrm = dis[s] * dis[d];
    atomicAdd(&agg[(size_t)d * HID + f], nrm * h[(size_t)s * HID + f]);
}

// ---------- finalize: agg += dis^2 * h (self-loop), + bias, relu ----------
__global__ __launch_bounds__(256) void k_fin_relu(float* __restrict__ agg,
                                                  const float* __restrict__ h,
                                                  const float* __restrict__ dis,
                                                  const float* __restrict__ b) {
    int t = blockIdx.x * 256 + threadIdx.x;
    if (t >= N_NODES * HID) return;
    int i = t >> 4;
    int j = t & 15;
    float di = dis[i];
    float v = agg[t] + di * di * h[t] + b[j];
    agg[t] = v > 0.0f ? v : 0.0f;
}

// ---------- finalize layer 3 (no bias/relu; bias applied after W3) ----------
__global__ __launch_bounds__(256) void k_fin_self(float* __restrict__ agg,
                                                  const float* __restrict__ h,
                                                  const float* __restrict__ dis) {
    int t = blockIdx.x * 256 + threadIdx.x;
    if (t >= N_NODES * HID) return;
    int i = t >> 4;
    float di = dis[i];
    agg[t] += di * di * h[t];
}

// ---------- o[N,16] = h[N,16] @ W[16,16] ----------
__global__ __launch_bounds__(256) void k_mm2(const float* __restrict__ h,
                                             const float* __restrict__ W,
                                             float* __restrict__ o) {
    __shared__ float Ws[HID * HID];
    if (threadIdx.x < HID * HID) Ws[threadIdx.x] = W[threadIdx.x];
    __syncthreads();
    int t = blockIdx.x * 256 + threadIdx.x;
    if (t >= N_NODES * HID) return;
    int i = t >> 4;
    int j = t & 15;
    const float* hr = h + (size_t)i * HID;
    float acc = 0.0f;
#pragma unroll
    for (int k = 0; k < HID; ++k) acc += hr[k] * Ws[k * HID + j];
    o[t] = acc;
}

// ---------- out[N,500] = a[N,16] @ W[16,500] + b ----------
__global__ __launch_bounds__(256) void k_mm3(const float* __restrict__ a,
                                             const float* __restrict__ W,
                                             const float* __restrict__ b,
                                             float* __restrict__ out) {
    int t = blockIdx.x * 256 + threadIdx.x;
    if (t >= N_NODES * OUT_DIM) return;
    int i = t / OUT_DIM;
    int j = t - i * OUT_DIM;
    const float* ar = a + (size_t)i * HID;
    float acc = b[j];
#pragma unroll
    for (int k = 0; k < HID; ++k) acc += ar[k] * W[k * OUT_DIM + j];
    out[t] = acc;
}

extern "C" void kernel_launch(void* const* d_in, const int* in_sizes, int n_in,
                              void* d_out, int out_size, void* d_ws, size_t ws_size,
                              hipStream_t stream) {
    const float* x  = (const float*)d_in[0];
    const int* ei   = (const int*)d_in[1];
    const float* W1 = (const float*)d_in[2];
    const float* b1 = (const float*)d_in[3];
    const float* W2 = (const float*)d_in[4];
    const float* b2 = (const float*)d_in[5];
    const float* W3 = (const float*)d_in[6];
    const float* b3 = (const float*)d_in[7];
    float* out = (float*)d_out;

    const int* src = ei;            // edge_index[0]
    const int* dst = ei + N_EDGES;  // edge_index[1]

    // workspace layout (floats): dis [100352 pad] | bufA [1.6M] | bufB [1.6M]
    float* dis  = (float*)d_ws;
    float* bufA = dis + 100352;
    float* bufB = bufA + (size_t)N_NODES * HID;

    const int B = 256;
    int gN   = (N_NODES + B - 1) / B;
    int gE   = (N_EDGES + B - 1) / B;
    int gNH  = (N_NODES * HID + B - 1) / B;
    int gE16 = (N_EDGES * 16 + B - 1) / B;
    int gOut = (N_NODES * OUT_DIM + B - 1) / B;
    size_t featBytes = (size_t)N_NODES * HID * sizeof(float);

    // degree -> dis = rsqrt(deg)
    k_set1<<<gN, B, 0, stream>>>(dis, N_NODES);
    k_deg<<<gE, B, 0, stream>>>(dst, dis, N_EDGES);
    k_rsqrt<<<gN, B, 0, stream>>>(dis, N_NODES);

    // layer 1: bufA = x@W1 ; bufB = relu(A_norm*bufA + b1)
    k_mm1<<<(N_NODES + 15) / 16, B, 0, stream>>>(x, W1, bufA);
    hipMemsetAsync(bufB, 0, featBytes, stream);
    k_agg<<<gE16, B, 0, stream>>>(src, dst, dis, bufA, bufB, N_EDGES);
    k_fin_relu<<<gNH, B, 0, stream>>>(bufB, bufA, dis, b1);

    // layer 2: bufA = bufB@W2 ; bufB = relu(A_norm*bufA + b2)
    k_mm2<<<gNH, B, 0, stream>>>(bufB, W2, bufA);
    hipMemsetAsync(bufB, 0, featBytes, stream);
    k_agg<<<gE16, B, 0, stream>>>(src, dst, dis, bufA, bufB, N_EDGES);
    k_fin_relu<<<gNH, B, 0, stream>>>(bufB, bufA, dis, b2);

    // layer 3: bufA = A_norm*bufB (aggregate at 16 dims!), out = bufA@W3 + b3
    hipMemsetAsync(bufA, 0, featBytes, stream);
    k_agg<<<gE16, B, 0, stream>>>(src, dst, dis, bufB, bufA, N_EDGES);
    k_fin_self<<<gNH, B, 0, stream>>>(bufA, bufB, dis);
    k_mm3<<<gOut, B, 0, stream>>>(bufA, W3, b3, out);
}

// Round 2
// 1001.398 us; speedup vs baseline: 1.3188x; 1.3188x over previous
//
#include <hip/hip_runtime.h>

#define N_NODES 100000
#define N_EDGES 3200000
#define IN_DIM 500
#define HID 16
#define OUT_DIM 500

// ================= degree / dis =================
__global__ void k_deg(const int* __restrict__ dst, int* __restrict__ cnt, int E) {
    int e = blockIdx.x * blockDim.x + threadIdx.x;
    if (e < E) atomicAdd(&cnt[dst[e]], 1);
}

__global__ void k_dis(const int* __restrict__ cnt, float* __restrict__ dis, int n) {
    int i = blockIdx.x * blockDim.x + threadIdx.x;
    if (i < n) dis[i] = rsqrtf((float)(cnt[i] + 1));  // +1 self-loop
}

// ================= CSR build: scan =================
__global__ __launch_bounds__(1024) void k_scanA(const int* __restrict__ cnt,
                                                int* __restrict__ rowptr,
                                                int* __restrict__ bsum) {
    __shared__ int sh[1024];
    int t = threadIdx.x;
    int i = blockIdx.x * 1024 + t;
    int v = (i < N_NODES) ? cnt[i] : 0;
    sh[t] = v;
    __syncthreads();
    for (int off = 1; off < 1024; off <<= 1) {
        int tmp = (t >= off) ? sh[t - off] : 0;
        __syncthreads();
        sh[t] += tmp;
        __syncthreads();
    }
    if (i < N_NODES) rowptr[i] = sh[t] - v;  // block-local exclusive
    if (t == 1023) bsum[blockIdx.x] = sh[1023];
}

__global__ __launch_bounds__(128) void k_scanB(int* __restrict__ bsum, int nb) {
    __shared__ int sh[128];
    int t = threadIdx.x;
    int v = (t < nb) ? bsum[t] : 0;
    sh[t] = v;
    __syncthreads();
    for (int off = 1; off < 128; off <<= 1) {
        int tmp = (t >= off) ? sh[t - off] : 0;
        __syncthreads();
        sh[t] += tmp;
        __syncthreads();
    }
    if (t < nb) bsum[t] = sh[t] - v;  // exclusive
}

__global__ void k_scanC(int* __restrict__ rowptr, const int* __restrict__ bsum) {
    int i = blockIdx.x * blockDim.x + threadIdx.x;
    if (i < N_NODES) rowptr[i] += bsum[i >> 10];
    if (i == 0) rowptr[N_NODES] = N_EDGES;
}

// ================= CSR fill =================
__global__ void k_fill(const int* __restrict__ src, const int* __restrict__ dst,
                       const int* __restrict__ rowptr, int* __restrict__ cursor,
                       int* __restrict__ csr, int E) {
    int e = blockIdx.x * blockDim.x + threadIdx.x;
    if (e < E) {
        int d = dst[e];
        int p = rowptr[d] + atomicAdd(&cursor[d], 1);
        csr[p] = src[e];
    }
}

// ================= hp[N,16] = dis * (x[N,500] @ W[500,16]) =================
__global__ __launch_bounds__(256) void k_mm1(const float* __restrict__ x,
                                             const float* __restrict__ W,
                                             const float* __restrict__ dis,
                                             float* __restrict__ hp) {
    __shared__ float Ws[IN_DIM * HID];
    for (int t = threadIdx.x; t < IN_DIM * HID; t += 256) Ws[t] = W[t];
    __syncthreads();
    int i = blockIdx.x * 16 + (threadIdx.x >> 4);
    int j = threadIdx.x & 15;
    if (i >= N_NODES) return;
    const float4* xr = (const float4*)(x + (size_t)i * IN_DIM);
    float acc = 0.0f;
#pragma unroll 5
    for (int k4 = 0; k4 < IN_DIM / 4; ++k4) {
        float4 v = xr[k4];
        acc += v.x * Ws[(4 * k4 + 0) * HID + j];
        acc += v.y * Ws[(4 * k4 + 1) * HID + j];
        acc += v.z * Ws[(4 * k4 + 2) * HID + j];
        acc += v.w * Ws[(4 * k4 + 3) * HID + j];
    }
    hp[(size_t)i * HID + j] = dis[i] * acc;
}

// ================= hp[N,16] = dis * (o[N,16] @ W[16,16]) =================
__global__ __launch_bounds__(256) void k_mm2(const float* __restrict__ o,
                                             const float* __restrict__ W,
                                             const float* __restrict__ dis,
                                             float* __restrict__ hp) {
    __shared__ float Ws[HID * HID];
    if (threadIdx.x < HID * HID) Ws[threadIdx.x] = W[threadIdx.x];
    __syncthreads();
    int t = blockIdx.x * 256 + threadIdx.x;
    if (t >= N_NODES * HID) return;
    int i = t >> 4;
    int j = t & 15;
    const float* orow = o + (size_t)i * HID;
    float acc = 0.0f;
#pragma unroll
    for (int k = 0; k < HID; ++k) acc += orow[k] * Ws[k * HID + j];
    hp[t] = dis[i] * acc;
}

// ================= hp = dis * o (elementwise, layer-3 pre-agg) =================
__global__ void k_scale(const float* __restrict__ o, const float* __restrict__ dis,
                        float* __restrict__ hp) {
    int t = blockIdx.x * blockDim.x + threadIdx.x;
    if (t < N_NODES * HID) hp[t] = dis[t >> 4] * o[t];
}

// ================= gather: o[d] = [relu](dis[d]*(sum hp[src] + hp[d]) [+ b]) ====
template <int RELU>
__global__ __launch_bounds__(256) void k_gather(const int* __restrict__ rowptr,
                                                const int* __restrict__ csr,
                                                const float* __restrict__ dis,
                                                const float* __restrict__ hp,
                                                const float* __restrict__ b,
                                                float* __restrict__ o) {
    int g = threadIdx.x >> 4;   // 16 node-groups per block
    int f = threadIdx.x & 15;   // feature lane
    int d = blockIdx.x * 16 + g;
    int start = rowptr[d];
    int end = rowptr[d + 1];
    float s = 0.0f;
    for (int e0 = start; e0 < end; e0 += 16) {
        int idx = e0 + f;
        int sid = (idx < end) ? csr[idx] : 0;
        int m = end - e0;
        if (m > 16) m = 16;
        for (int j = 0; j < m; ++j) {
            int sj = __shfl(sid, j, 16);  // uniform within the 16-lane group
            s += hp[(size_t)sj * HID + f];
        }
    }
    float di = dis[d];
    float v = di * (s + hp[(size_t)d * HID + f]);
    if (RELU) {
        v += b[f];
        v = v > 0.0f ? v : 0.0f;
    }
    o[(size_t)d * HID + f] = v;
}

// ================= out[N,500] = a[N,16] @ W[16,500] + b =================
// register-blocked: 4 rows x 4 cols per thread, W in LDS (ds_read_b128)
__global__ __launch_bounds__(256) void k_mm3(const float* __restrict__ a,
                                             const float* __restrict__ W,
                                             const float* __restrict__ b,
                                             float* __restrict__ out) {
    __shared__ float Ws[HID * OUT_DIM];  // 32000 B
    __shared__ float bs[OUT_DIM];
    for (int t = threadIdx.x; t < HID * OUT_DIM; t += 256) Ws[t] = W[t];
    for (int t = threadIdx.x; t < OUT_DIM; t += 256) bs[t] = b[t];
    __syncthreads();
    int ct = threadIdx.x & 127;  // 0..127 (125 active)
    int rt = threadIdx.x >> 7;   // 0..1
    int r0 = blockIdx.x * 8 + rt * 4;
    float areg[4][16];
#pragma unroll
    for (int rr = 0; rr < 4; ++rr) {
        const float4* ap = (const float4*)(a + (size_t)(r0 + rr) * HID);
        float4 v0 = ap[0], v1 = ap[1], v2 = ap[2], v3 = ap[3];
        areg[rr][0] = v0.x;  areg[rr][1] = v0.y;  areg[rr][2] = v0.z;  areg[rr][3] = v0.w;
        areg[rr][4] = v1.x;  areg[rr][5] = v1.y;  areg[rr][6] = v1.z;  areg[rr][7] = v1.w;
        areg[rr][8] = v2.x;  areg[rr][9] = v2.y;  areg[rr][10] = v2.z; areg[rr][11] = v2.w;
        areg[rr][12] = v3.x; areg[rr][13] = v3.y; areg[rr][14] = v3.z; areg[rr][15] = v3.w;
    }
    if (ct >= 125) return;
    int j0 = ct * 4;
    float acc[4][4];
#pragma unroll
    for (int rr = 0; rr < 4; ++rr) {
        acc[rr][0] = bs[j0];
        acc[rr][1] = bs[j0 + 1];
        acc[rr][2] = bs[j0 + 2];
        acc[rr][3] = bs[j0 + 3];
    }
#pragma unroll
    for (int k = 0; k < HID; ++k) {
        float4 w = *(const float4*)&Ws[k * OUT_DIM + j0];
#pragma unroll
        for (int rr = 0; rr < 4; ++rr) {
            acc[rr][0] += areg[rr][k] * w.x;
            acc[rr][1] += areg[rr][k] * w.y;
            acc[rr][2] += areg[rr][k] * w.z;
            acc[rr][3] += areg[rr][k] * w.w;
        }
    }
#pragma unroll
    for (int rr = 0; rr < 4; ++rr) {
        float4 r = make_float4(acc[rr][0], acc[rr][1], acc[rr][2], acc[rr][3]);
        *(float4*)&out[(size_t)(r0 + rr) * OUT_DIM + j0] = r;
    }
}

extern "C" void kernel_launch(void* const* d_in, const int* in_sizes, int n_in,
                              void* d_out, int out_size, void* d_ws, size_t ws_size,
                              hipStream_t stream) {
    const float* x  = (const float*)d_in[0];
    const int* ei   = (const int*)d_in[1];
    const float* W1 = (const float*)d_in[2];
    const float* b1 = (const float*)d_in[3];
    const float* W2 = (const float*)d_in[4];
    const float* b2 = (const float*)d_in[5];
    const float* W3 = (const float*)d_in[6];
    const float* b3 = (const float*)d_in[7];
    float* out = (float*)d_out;

    const int* src = ei;
    const int* dst = ei + N_EDGES;

    // workspace layout (bytes)
    char* w = (char*)d_ws;
    float* dis    = (float*)(w);                 // 100352 f
    int*   cnt    = (int*)(w + 401408);          // 100352 i  (reused as cursor)
    int*   rowptr = (int*)(w + 802816);          // 100608 i
    int*   bsum   = (int*)(w + 1205248);         // 128 i
    int*   csr    = (int*)(w + 1205760);         // 3.2M i
    float* hp     = (float*)(w + 14005760);      // 1.6M f
    float* o      = (float*)(w + 20405760);      // 1.6M f
    // total ~26.81 MB

    const int B = 256;
    int gN   = (N_NODES + B - 1) / B;
    int gE   = (N_EDGES + B - 1) / B;
    int gNH  = (N_NODES * HID + B - 1) / B;   // 6250
    int gG   = N_NODES / 16;                  // 6250 (exact)
    int gMM3 = N_NODES / 8;                   // 12500 (exact)
    int gScanA = (N_NODES + 1023) / 1024;     // 98

    // ---- degree & dis ----
    hipMemsetAsync(cnt, 0, N_NODES * sizeof(int), stream);
    k_deg<<<gE, B, 0, stream>>>(dst, cnt, N_EDGES);
    k_dis<<<gN, B, 0, stream>>>(cnt, dis, N_NODES);

    // ---- CSR build ----
    k_scanA<<<gScanA, 1024, 0, stream>>>(cnt, rowptr, bsum);
    k_scanB<<<1, 128, 0, stream>>>(bsum, gScanA);
    k_scanC<<<gN, B, 0, stream>>>(rowptr, bsum);
    hipMemsetAsync(cnt, 0, N_NODES * sizeof(int), stream);  // cursor
    k_fill<<<gE, B, 0, stream>>>(src, dst, rowptr, cnt, csr, N_EDGES);

    // ---- layer 1 ----
    k_mm1<<<(N_NODES + 15) / 16, B, 0, stream>>>(x, W1, dis, hp);
    k_gather<1><<<gG, B, 0, stream>>>(rowptr, csr, dis, hp, b1, o);

    // ---- layer 2 ----
    k_mm2<<<gNH, B, 0, stream>>>(o, W2, dis, hp);
    k_gather<1><<<gG, B, 0, stream>>>(rowptr, csr, dis, hp, b2, o);

    // ---- layer 3: aggregate at 16 dims, then W3 ----
    k_scale<<<gNH, B, 0, stream>>>(o, dis, hp);
    k_gather<0><<<gG, B, 0, stream>>>(rowptr, csr, dis, hp, b3, o);
    k_mm3<<<gMM3, B, 0, stream>>>(o, W3, b3, out);
}